// Round 1
// baseline (84.793 us; speedup 1.0000x reference)
//
#include <hip/hip_runtime.h>

// Problem constants (match reference)
#define GS    20
#define PARAM 40
#define NSYS  80             // B * A = 8 * 10
#define NLOC  (GS * PARAM)   // 800 unknowns per system
#define NTH   400
#define INNER 5              // Jacobi sweeps for G=S^-1 Ng, c=S^-1 v (||B||~0.33); MUST be odd
#define OUTER 3              // block-preconditioned sweeps (rho ~ 0.15); R6/R7: absmax unchanged

// Solve (I (x) S + M (x) Ng) x = v, then clip to [-1,1].
// Block form, row i:  x_i = S^-1 v_i - (S^-1 Ng) sum_j M[i,j] x_j  =  c_i - G z_i
// Setup (inner): G and c via point-Jacobi on S. Outer: phase1 Z = M X, phase2 x' = c - G Z.
//
// LESSONS (do not regress):
//  - R6: per-thread scalar global reads (stride 160B) are uncoalesced — keep ALL global
//    access as lane-contiguous float4.
//  - R6/R7: `#pragma unroll` on the INNER/OUTER sweep loops explodes live registers
//    -> scratch spills -> FETCH 2.4->11.8 MB, WRITE 0.25->22.5 MB, dispatch 14->48 us.
//    Keep sweep loops ROLLED.
//  - R8 (this round): the old sr0..sr3 "register cache" (160 floats) was silently
//    rematerialized from LDS each sweep anyway — made the LDS reads explicit and fused
//    the G/c k-loops so each S' row-block is streamed once per sweep.
//  - R8: c-solve is now BALANCED across all 400 threads (each thread: 4 G-rows + a
//    2-row pair of c-column u%20 => 240 FMA/sweep) instead of u<20 threads doing 320.
//    FP summation order per element is unchanged -> absmax must stay 0.00390625.
//  - R8: final inner sweep writes G ROW-major (sGrow); outer-phase row gather becomes
//    20 ds_read_b128 instead of 80 scalar ds_read_b32. mrow staged as float4[5].
__global__ __launch_bounds__(NTH) void gliam_solve(
    const float* __restrict__ mat,   // (NSYS, GS, GS)
    const float* __restrict__ val,   // (NSYS, GS, PARAM)
    const float* __restrict__ S,     // (PARAM, PARAM)
    const float* __restrict__ Ng,    // (PARAM, PARAM)
    float* __restrict__ out)         // (NSYS, GS, PARAM)
{
    __shared__ float4 sSoff[PARAM * 11];   // D^-1 S, diag zeroed, rows padded to 44 floats
    __shared__ float4 sNgP [PARAM * 11];   // raw Ng, padded
    __shared__ float  sRD  [PARAM];        // 1 / S[p][p]
    __shared__ float  sM   [GS * GS];
    __shared__ float4 sGc  [2][PARAM * 11]; // G column-major: col u at [u*11 .. u*11+9]
    __shared__ float4 sGrow[PARAM * 11];    // final G row-major: row r at [r*11 .. r*11+9]
    __shared__ float4 sXv  [2][NLOC / 4];   // state X (also c-iteration buffer)
    __shared__ float4 sZ   [NLOC / 4];      // Z = M·X

    const int sys = blockIdx.x;
    const int t   = threadIdx.x;
    const int pb  = t % 10;   // float4 row-block: rows 4pb..4pb+3
    const int u   = t / 10;   // 0..39: G column index
    const int uc  = u % 20;   // balanced c-solve: this thread's c column
    const int h   = u / 20;   // which row-pair of row-block pb this thread owns for c

    // ---- stage (coalesced float4) + fold D^-1 into S rows ----
    {
        const float rd = 1.0f / S[u * PARAM + u];    // 40 distinct addrs, L1 broadcast
        float4 a = ((const float4*)S)[t];            // row u, float4 block pb (coalesced)
        a.x *= rd; a.y *= rd; a.z *= rd; a.w *= rd;
        if (pb == (u >> 2)) ((float*)&a)[u & 3] = 0.0f;   // zero diagonal entry
        sSoff[u * 11 + pb] = a;
        sNgP [u * 11 + pb] = ((const float4*)Ng)[t]; // coalesced
    }
    if (t < PARAM) sRD[t] = 1.0f / S[t * PARAM + t];
    sM[t] = mat[sys * GS * GS + t];                  // GS*GS == NTH == 400, coalesced
    __syncthreads();

    // ---- per-thread constants: Ngd column u; c0 = D^-1 v staged to LDS ----
    float4 ngd;
    {
        const float* Ngf = (const float*)sNgP;       // LDS transpose-gather (once)
        const float rd0 = sRD[4*pb+0], rd1 = sRD[4*pb+1],
                    rd2 = sRD[4*pb+2], rd3 = sRD[4*pb+3];
        ngd.x = Ngf[(4*pb+0)*44 + u] * rd0;
        ngd.y = Ngf[(4*pb+1)*44 + u] * rd1;
        ngd.z = Ngf[(4*pb+2)*44 + u] * rd2;
        ngd.w = Ngf[(4*pb+3)*44 + u] * rd3;
        sGc[0][u*11 + pb] = ngd;                     // G0 = D^-1 Ng (column-major)
        if (u < GS) {
            const float4 v4 = *(const float4*)&val[sys*NLOC + u*PARAM + 4*pb]; // coalesced
            float4 vd;
            vd.x = v4.x * rd0; vd.y = v4.y * rd1; vd.z = v4.z * rd2; vd.w = v4.w * rd3;
            sXv[0][u*10 + pb] = vd;                  // c0 = D^-1 v
        }
    }
    __syncthreads();

    // this thread's c row-pair initial value (rows 4pb+2h, 4pb+2h+1 of column uc)
    const int cw = uc*PARAM + 4*pb + 2*h;            // float offset of the pair
    float vd2x, vd2y;
    {
        const float* c0f = (const float*)sXv[0];
        vd2x = c0f[cw];
        vd2y = c0f[cw + 1];
    }

    // S' row pointers (addresses depend only on pb/h -> wave-broadcast reads, conflict-free)
    const float4* const s0  = &sSoff[(4*pb+0)*11];
    const float4* const s1  = &sSoff[(4*pb+1)*11];
    const float4* const s2  = &sSoff[(4*pb+2)*11];
    const float4* const s3  = &sSoff[(4*pb+3)*11];
    const float4* const sc0 = &sSoff[(4*pb+2*h  )*11];
    const float4* const sc1 = &sSoff[(4*pb+2*h+1)*11];

    // ---- inner sweeps (ROLLED): fused G <- Ngd - B G ; c <- Vd - B c (balanced) ----
    for (int s = 0; s < INNER; ++s) {
        const int cur = s & 1, nxt = cur ^ 1;
        float4 accG = ngd;
        float  accC0 = vd2x, accC1 = vd2y;
        const float4* gcol = &sGc[cur][u * 11];
        const float4* ccol = &sXv[cur][uc * 10];
        #pragma unroll
        for (int k = 0; k < 10; ++k) {
            const float4 g  = gcol[k];
            const float4 c  = ccol[k];
            const float4 a0 = s0[k], a1 = s1[k], a2 = s2[k], a3 = s3[k];
            accG.x -= a0.x*g.x + a0.y*g.y + a0.z*g.z + a0.w*g.w;
            accG.y -= a1.x*g.x + a1.y*g.y + a1.z*g.z + a1.w*g.w;
            accG.z -= a2.x*g.x + a2.y*g.y + a2.z*g.z + a2.w*g.w;
            accG.w -= a3.x*g.x + a3.y*g.y + a3.z*g.z + a3.w*g.w;
            const float4 b0 = sc0[k], b1 = sc1[k];
            accC0 -= b0.x*c.x + b0.y*c.y + b0.z*c.z + b0.w*c.w;
            accC1 -= b1.x*c.x + b1.y*c.y + b1.z*c.z + b1.w*c.w;
        }
        if (s < INNER - 1) {
            sGc[nxt][u*11 + pb] = accG;              // column-major for next sweep
        } else {
            float* Gr = (float*)sGrow;               // final sweep: row-major scatter
            Gr[(4*pb+0)*44 + u] = accG.x;
            Gr[(4*pb+1)*44 + u] = accG.y;
            Gr[(4*pb+2)*44 + u] = accG.z;
            Gr[(4*pb+3)*44 + u] = accG.w;
        }
        {
            float* Xn = (float*)sXv[nxt];
            Xn[cw]     = accC0;
            Xn[cw + 1] = accC1;
        }
        __syncthreads();
    }
    // INNER odd -> final c buffer is sXv[1]; final G is sGrow (row-major)

    // ---- outer-loop registers: G rows p, p+20 (float4 reads now); c values; M row ----
    const int i = t / GS;        // block-row 0..19
    const int p = t % GS;        // component 0..19; partner p+20
    float4 gr0[10], gr1[10];
    #pragma unroll
    for (int k = 0; k < 10; ++k) {
        gr0[k] = sGrow[ p      * 11 + k];
        gr1[k] = sGrow[(p + 20)* 11 + k];
    }
    const float c0 = ((const float*)sXv[1])[i*PARAM + p];
    const float c1 = ((const float*)sXv[1])[i*PARAM + p + 20];
    float4 mrow4[5];
    if (t < 200) {
        const int zi = t / 10;
        #pragma unroll
        for (int k = 0; k < 5; ++k) mrow4[k] = *(const float4*)&sM[zi*GS + 4*k];
    }
    // (reads only — all data final behind the last inner barrier; x0 = c in sXv[1])

    int cur = 1;
    for (int it = 0; it < OUTER; ++it) {   // ROLLED (see header note)
        // phase 1: Z[zi][cc4] = sum_j M[zi,j] * X[j][cc4]  (j order preserved)
        if (t < 200) {
            const int zi = t / 10, cc = t - (t/10)*10;
            const float4* X4 = sXv[cur];
            float4 acc = make_float4(0.f, 0.f, 0.f, 0.f);
            #pragma unroll
            for (int jb = 0; jb < 5; ++jb) {
                const float4 m  = mrow4[jb];
                const float4 x0 = X4[(4*jb+0)*10 + cc];
                const float4 x1 = X4[(4*jb+1)*10 + cc];
                const float4 x2 = X4[(4*jb+2)*10 + cc];
                const float4 x3 = X4[(4*jb+3)*10 + cc];
                acc.x += m.x*x0.x; acc.y += m.x*x0.y; acc.z += m.x*x0.z; acc.w += m.x*x0.w;
                acc.x += m.y*x1.x; acc.y += m.y*x1.y; acc.z += m.y*x1.z; acc.w += m.y*x1.w;
                acc.x += m.z*x2.x; acc.y += m.z*x2.y; acc.z += m.z*x2.z; acc.w += m.z*x2.w;
                acc.x += m.w*x3.x; acc.y += m.w*x3.y; acc.z += m.w*x3.z; acc.w += m.w*x3.w;
            }
            sZ[zi*10 + cc] = acc;
        }
        __syncthreads();
        // phase 2: x'_{i,p} = c - Grow_p · Z_i  (two outputs share Z_i reads)
        const float4* Z4 = &sZ[i*10];
        float a0 = 0.f, a1 = 0.f;
        #pragma unroll
        for (int k = 0; k < 10; ++k) {
            const float4 z = Z4[k];
            a0 += gr0[k].x*z.x + gr0[k].y*z.y + gr0[k].z*z.z + gr0[k].w*z.w;
            a1 += gr1[k].x*z.x + gr1[k].y*z.y + gr1[k].z*z.z + gr1[k].w*z.w;
        }
        const float x0n = c0 - a0, x1n = c1 - a1;
        if (it == OUTER - 1) {
            // epilogue: advrelu(lo=-1,hi=1) == clip
            out[sys*NLOC + i*PARAM + p   ] = fminf(fmaxf(x0n, -1.f), 1.f);
            out[sys*NLOC + i*PARAM + p+20] = fminf(fmaxf(x1n, -1.f), 1.f);
        } else {
            ((float*)sXv[cur ^ 1])[i*PARAM + p   ] = x0n;
            ((float*)sXv[cur ^ 1])[i*PARAM + p+20] = x1n;
            __syncthreads();
            cur ^= 1;
        }
    }
}

extern "C" void kernel_launch(void* const* d_in, const int* in_sizes, int n_in,
                              void* d_out, int out_size, void* d_ws, size_t ws_size,
                              hipStream_t stream) {
    const float* mat = (const float*)d_in[0];  // 8*10*20*20 = 32000
    const float* val = (const float*)d_in[1];  // 8*10*20*40 = 64000
    const float* S   = (const float*)d_in[2];  // 40*40
    const float* Ng  = (const float*)d_in[3];  // 40*40
    float* out = (float*)d_out;                // 64000 f32

    gliam_solve<<<NSYS, NTH, 0, stream>>>(mat, val, S, Ng, out);
}